// Round 9
// baseline (502.065 us; speedup 1.0000x reference)
//
#include <hip/hip_runtime.h>
#include <hip/hip_bf16.h>
#include <stdint.h>

#define TLEN 2048
#define CDIM 2048
#define BDIM 2
#define HDIM 16
#define DHEAD 128
// Q/K packed at stride 2*CDIM; V goes to a separate transposed buffer.
#define QROW ((size_t)(2 * CDIM))

typedef __bf16 bf16x8 __attribute__((ext_vector_type(8)));
typedef float f32x4 __attribute__((ext_vector_type(4)));

__device__ __forceinline__ uint16_t f32_to_bf16(float f) {
    uint32_t u = __builtin_bit_cast(uint32_t, f);
    uint32_t r = (u + 0x7FFFu + ((u >> 16) & 1u)) >> 16;
    return (uint16_t)r;
}
__device__ __forceinline__ float bf16_to_f32(uint32_t h) {
    uint32_t u = h << 16;
    return __builtin_bit_cast(float, u);
}

// async global->LDS, 16B per lane. LDS dest = wave-uniform base + lane*16;
// global source address is per-lane (gather) — used for swizzled staging.
__device__ __forceinline__ void gload_lds16(const uint16_t* g, uint16_t* l) {
    __builtin_amdgcn_global_load_lds(
        (const __attribute__((address_space(1))) uint32_t*)g,
        (__attribute__((address_space(3))) uint32_t*)l, 16, 0, 0);
}

// ---------------- elementwise f32 -> bf16 ----------------
__global__ void cvt_f32_bf16(const float* __restrict__ in, uint16_t* __restrict__ out, int n) {
    int i = (blockIdx.x * blockDim.x + threadIdx.x) * 4;
    if (i + 3 < n) {
        float4 f = *reinterpret_cast<const float4*>(in + i);
        ushort4 o;
        o.x = f32_to_bf16(f.x);
        o.y = f32_to_bf16(f.y);
        o.z = f32_to_bf16(f.z);
        o.w = f32_to_bf16(f.w);
        *reinterpret_cast<ushort4*>(out + i) = o;
    }
}

// ---------------- transpose + cast: in [R][Cc] f32 -> out [Cc][R] bf16 ----------------
__global__ __launch_bounds__(256) void transpose_cvt(const float* __restrict__ in,
                                                     uint16_t* __restrict__ out,
                                                     int R, int Cc) {
    __shared__ uint16_t tile[64][65];
    int c0 = blockIdx.x * 64;
    int r0 = blockIdx.y * 64;
    int tc = threadIdx.x & 63;
    int t4 = threadIdx.x >> 6;  // 0..3
    for (int rr = t4; rr < 64; rr += 4) {
        tile[rr][tc] = f32_to_bf16(in[(size_t)(r0 + rr) * Cc + c0 + tc]);
    }
    __syncthreads();
    int wr = threadIdx.x & 63;
    for (int cc = t4; cc < 64; cc += 4) {
        out[(size_t)(c0 + cc) * R + r0 + wr] = tile[wr][cc];
    }
}

// ====== 256x256 bf16 MFMA GEMM: half-unit LDS ring, 2-cluster/3-barrier tile ======
// (R6 body, verbatim — measured 128.6 µs QKV, no spill. R7's chunk-pipelined TILE
// coincided with two consecutive container failures and is shelved pending a
// passing control; this body is the bisect baseline.)
// C[M][N] = A[M][K] * Bt[N][K]^T. 512 thr = 8 waves (2M x 4N); wave tile 128x64;
// BK=64; LDS ring of 4 half-unit slots per operand (even tiles slots 0/1, odd 2/3);
// tile t stages tile t+2's units. vmcnt ring: end-of-T vmcnt(8) retires T-1's 8
// stages (which loaded T+1). Edges: T+2>=nt -> no stage; T+1<nt -> vmcnt(0).
// Barriers only at true hazard points: B-slot WAR, A-slot WAR, t+1 visibility.
// Frag-live = aA(32)+bB(32) = 64 VGPR (R5's 96-VGPR read-ahead spilled: tripwire).
// XCD mapping: rectangular per-XCD tiling (R4; FETCH 176->90 MB verified).
// LDS swizzle: 16B-block c' = c ^ (row&7) via pre-swizzled global source.
// MODE 0: f32 out. MODE 2: QKV split — Q/K cols -> packed bf16 [M][2*CDIM],
// V cols -> transposed bf16 Vt[(b*16+h)*128+d][t].

#define RD8(P, OFF) (*reinterpret_cast<const bf16x8*>((P) + (OFF)))

#define RDA(DST, P, MB)                                         \
    _Pragma("unroll") for (int mi = 0; mi < 4; mi++) {          \
        DST[mi][0] = RD8(P, rdAo + ((MB) + mi) * 1024 + kblk0); \
        DST[mi][1] = RD8(P, rdAo + ((MB) + mi) * 1024 + kblk1); \
    }

#define RDB4(DST, P)                                   \
    _Pragma("unroll") for (int ni = 0; ni < 4; ni++) { \
        DST[ni][0] = RD8(P, rdBo + ni * 1024 + kblk0); \
        DST[ni][1] = RD8(P, rdBo + ni * 1024 + kblk1); \
    }

// 32 MFMA: k outer so each acc's two updates are 16 instructions apart.
#define MFMA32(MB)                                                    \
    _Pragma("unroll") for (int kk = 0; kk < 2; kk++)                  \
    _Pragma("unroll") for (int mi = 0; mi < 4; mi++)                  \
    _Pragma("unroll") for (int ni = 0; ni < 4; ni++)                  \
        acc[(MB) + mi][ni] = __builtin_amdgcn_mfma_f32_16x16x32_bf16( \
            aA[mi][kk], bB[ni][kk], acc[(MB) + mi][ni], 0, 0, 0);

#define TILE(S, T)                                           \
    {                                                        \
        const int k0 = (T) * 64;                             \
        const uint16_t* pA = As + ((S) + wrow) * 8192;       \
        const uint16_t* pB = Bs + ((S) + bsel) * 8192;       \
        RDB4(bB, pB)                                         \
        RDA(aA, pA, 0)                                       \
        asm volatile("s_waitcnt lgkmcnt(8)" ::: "memory");   \
        __builtin_amdgcn_s_barrier(); /* B reads done */     \
        if ((T) + 2 < nt) {                                  \
            stB((S), 0, k0 + 128);                           \
            stB((S), 1, k0 + 128);                           \
        }                                                    \
        asm volatile("s_waitcnt lgkmcnt(0)" ::: "memory");   \
        __builtin_amdgcn_sched_barrier(0);                   \
        __builtin_amdgcn_s_setprio(1);                       \
        MFMA32(0)                                            \
        __builtin_amdgcn_s_setprio(0);                       \
        RDA(aA, pA, 4)                                       \
        asm volatile("s_waitcnt lgkmcnt(0)" ::: "memory");   \
        __builtin_amdgcn_s_barrier(); /* A reads done */     \
        if ((T) + 2 < nt) {                                  \
            stA((S), 0, k0 + 128);                           \
            stA((S), 1, k0 + 128);                           \
        }                                                    \
        __builtin_amdgcn_sched_barrier(0);                   \
        __builtin_amdgcn_s_setprio(1);                       \
        MFMA32(4)                                            \
        __builtin_amdgcn_s_setprio(0);                       \
        if ((T) + 2 < nt) {                                  \
            asm volatile("s_waitcnt vmcnt(8)" ::: "memory"); \
        } else if ((T) + 1 < nt) {                           \
            asm volatile("s_waitcnt vmcnt(0)" ::: "memory"); \
        }                                                    \
        __builtin_amdgcn_s_barrier(); /* t+1 visible */      \
        __builtin_amdgcn_sched_barrier(0);                   \
    }

template <int MODE>
__global__ __launch_bounds__(512, 2) void gemm_bf16_256(const uint16_t* __restrict__ A,
                                                        const uint16_t* __restrict__ Bt,
                                                        void* __restrict__ Cp,
                                                        uint16_t* __restrict__ vt,
                                                        int M, int N, int K, int xm) {
    __shared__ __align__(16) uint16_t lds[65536];  // 128 KiB
    uint16_t* const As = lds;          // 4 ring slots x 8192 elems (128 rows x 64 K)
    uint16_t* const Bs = lds + 32768;  // 4 ring slots

    const int tid = threadIdx.x;
    const int wave = tid >> 6;
    const int lane = tid & 63;
    const int l15 = lane & 15;
    const int quad = lane >> 4;
    const int wrow = wave >> 2;  // 0..1 -> A half
    const int wcol = wave & 3;   // 0..3
    const int bsel = wcol >> 1;  // B half

    // rectangular XCD mapping (bijective; requires xm|gm and (8/xm)|gn).
    const int gm = gridDim.y, gn = gridDim.x;
    const int flat = blockIdx.y * gn + blockIdx.x;
    const int xcd = flat & 7;
    const int j = flat >> 3;  // 0 .. gm*gn/8 - 1
    const int xn = 8 / xm;
    const int RM = gm / xm;  // rect height (m-blocks)
    const int RN = gn / xn;  // rect width (n-blocks)
    const int m_blk = (xcd / xn) * RM + (j % RM);
    const int n_blk = (xcd % xn) * RN + (j / RM);
    const int m0 = m_blk * 256;
    const int n0 = n_blk * 256;

    // staging: lane -> row (lane>>3) within 8-row slab, source 16B-block
    // (lane&7) ^ (lane>>3) so that LDS (r, c') holds global block c' ^ (r&7).
    const int srow = wave * 8 + (lane >> 3);
    const int scol = ((lane & 7) ^ (lane >> 3)) * 8;
    const uint16_t* Ag = A + (size_t)(m0 + srow) * K + scol;
    const uint16_t* Bg = Bt + (size_t)(n0 + srow) * K + scol;
    const int ldsoff = wave * 512;

    // frag-read constants within a half-unit (row&7 == l15&7 for all frag rows)
    const int rdAo = l15 * 64;
    const int rdBo = ((wcol & 1) * 64 + l15) * 64;
    const int kblk0 = (quad ^ (l15 & 7)) * 8;
    const int kblk1 = ((4 + quad) ^ (l15 & 7)) * 8;

    const int nt = K >> 6;
    f32x4 acc[8][4] = {};
    bf16x8 aA[4][2], bB[4][2];

    auto stA = [&](int sb, int h, int kk) {
        const uint16_t* s = Ag + (size_t)(h * 128) * K + kk;
        uint16_t* d = As + (sb + h) * 8192 + ldsoff;
        gload_lds16(s, d);
        gload_lds16(s + (size_t)64 * K, d + 4096);
    };
    auto stB = [&](int sb, int h, int kk) {
        const uint16_t* s = Bg + (size_t)(h * 128) * K + kk;
        uint16_t* d = Bs + (sb + h) * 8192 + ldsoff;
        gload_lds16(s, d);
        gload_lds16(s + (size_t)64 * K, d + 4096);
    };

    // prologue: tile 0 -> slots 0/1, tile 1 -> slots 2/3 (16 loads);
    // vmcnt(8) retires tile-0 units; barrier gives cross-wave visibility.
    stB(0, 0, 0);
    stB(0, 1, 0);
    stA(0, 0, 0);
    stA(0, 1, 0);
    stB(2, 0, 64);
    stB(2, 1, 64);
    stA(2, 0, 64);
    stA(2, 1, 64);
    asm volatile("s_waitcnt vmcnt(8)" ::: "memory");
    __builtin_amdgcn_s_barrier();
    __builtin_amdgcn_sched_barrier(0);

    for (int t = 0; t < nt; t += 2) {
        TILE(0, t)
        TILE(2, t + 1)
    }

    const bool vmode = (MODE == 2) && (n0 >= 2 * CDIM);  // block-uniform
#pragma unroll
    for (int mi = 0; mi < 8; mi++)
#pragma unroll
        for (int ni = 0; ni < 4; ni++) {
            if (vmode) {
                // V cols: write transposed into Vt[(b*16+h)*128+d][t].
                int col = n0 + wcol * 64 + ni * 16 + l15;
                int vcol = col - 2 * CDIM;
                int hh = vcol >> 7, d = vcol & 127;
                int rowm = m0 + wrow * 128 + mi * 16 + quad * 4;
                int bb = rowm >> 11, tt = rowm & 2047;
                uint32_t lo = (uint32_t)f32_to_bf16(acc[mi][ni][0]) |
                              ((uint32_t)f32_to_bf16(acc[mi][ni][1]) << 16);
                uint32_t hi = (uint32_t)f32_to_bf16(acc[mi][ni][2]) |
                              ((uint32_t)f32_to_bf16(acc[mi][ni][3]) << 16);
                *reinterpret_cast<uint2*>(
                    vt + ((size_t)((bb * HDIM + hh) * DHEAD + d)) * TLEN + tt) =
                    make_uint2(lo, hi);
            } else {
#pragma unroll
                for (int r = 0; r < 4; r++) {
                    int row = m0 + wrow * 128 + mi * 16 + quad * 4 + r;
                    int col = n0 + wcol * 64 + ni * 16 + l15;
                    float v = acc[mi][ni][r];
                    if (MODE == 2)
                        ((uint16_t*)Cp)[(size_t)row * (2 * CDIM) + col] = f32_to_bf16(v);
                    else if (MODE == 1)
                        ((uint16_t*)Cp)[(size_t)row * N + col] = f32_to_bf16(v);
                    else
                        ((float*)Cp)[(size_t)row * N + col] = v;
                }
            }
        }
}

// ---------------- MFMA flash attention v4: T14 reg-staged K/V prefetch ----------------
// R9 change: the old loop did {barrier; issue 8 global_load_lds; __syncthreads()}
// per tile — __syncthreads drains vmcnt(0), so every tile paid full HBM
// latency+transfer serially between compute phases (only 2 blocks/CU of TLP to
// hide it). Now tile t+1's K/V are loaded into REGISTERS (8x dwordx4, +32 VGPR)
// BEFORE tile t's compute (loads fly under ~1500 cyc of MFMA+softmax), and
// written to LDS after the post-compute barrier (ds_write_b128 x8, ~100 cyc
// exposed). Same koff/voff swizzled global offsets; ds_write dest = the
// gload_lds implicit dest (base + lane*16B). 2 wave-uniform barriers/tile.
#define ATT_C1 0.12751743f
#define ATT_C2 17.3123405f

__global__ __launch_bounds__(256) void attn_mfma3(const uint16_t* __restrict__ qkv,
                                                  const uint16_t* __restrict__ vtg,
                                                  uint16_t* __restrict__ y) {
    __shared__ __align__(16) uint16_t Ks[64 * 128];    // swizzled: c' = c ^ (key&15)
    __shared__ __align__(16) uint16_t Vts[128 * 64];   // swizzled: c' = c ^ (d&7)
    __shared__ __align__(16) uint16_t Ps[4][32 * 72];  // per-wave P [q][key]

    const int tid = threadIdx.x;
    const int wave = tid >> 6;
    const int lane = tid & 63;
    const int l15 = lane & 15;
    const int quad = lane >> 4;
    const int h = blockIdx.y;
    const int b = blockIdx.z;
    const int qblk = (int)gridDim.x - 1 - (int)blockIdx.x;
    const int qbase = qblk * 128 + wave * 32;
    const int kmax = qbase + 31;

    const uint16_t* kg = qkv + (size_t)b * TLEN * QROW + CDIM + h * DHEAD;
    const uint16_t* vg = vtg + (size_t)(b * HDIM + h) * DHEAD * TLEN;
    uint16_t* PsW = Ps[wave];

    int koff[4], voff[4];
#pragma unroll
    for (int i = 0; i < 4; i++) {
        int Lb = (wave * 4 + i) * 64 + lane;
        int key = Lb >> 4;
        int ck = (Lb & 15) ^ (key & 15);
        koff[i] = key * (int)QROW + ck * 8;
        int d = Lb >> 3;
        int cv = (Lb & 7) ^ (d & 7);
        voff[i] = d * TLEN + cv * 8;
    }

    bf16x8 qfrag[2][4];
#pragma unroll
    for (int m = 0; m < 2; m++) {
        const uint16_t* qp =
            qkv + (size_t)(b * TLEN + qbase + m * 16 + l15) * QROW + h * DHEAD + quad * 8;
#pragma unroll
        for (int kc = 0; kc < 4; kc++)
            qfrag[m][kc] = *reinterpret_cast<const bf16x8*>(qp + kc * 32);
    }

    f32x4 oacc[2][8] = {};
    float psum[2] = {0.f, 0.f};

    const int diagT = qblk * 2 + (wave >> 1);
    const int ntiles = qblk * 2 + 2;

    // stage tile 0 directly (global->LDS); __syncthreads drains it.
#pragma unroll
    for (int i = 0; i < 4; i++) {
        gload_lds16(kg + koff[i], Ks + (wave * 4 + i) * 512);
        gload_lds16(vg + voff[i], Vts + (wave * 4 + i) * 512);
    }
    __syncthreads();

    uint4 kpre[4], vpre[4];
    for (int t = 0; t < ntiles; t++) {
        const bool havenext = (t + 1 < ntiles);
        if (havenext) {
            const uint16_t* kj = kg + (size_t)(t + 1) * 64 * QROW;
            const uint16_t* vj = vg + (t + 1) * 64;
#pragma unroll
            for (int i = 0; i < 4; i++) {
                kpre[i] = *reinterpret_cast<const uint4*>(kj + koff[i]);
                vpre[i] = *reinterpret_cast<const uint4*>(vj + voff[i]);
            }
        }

        if (t <= diagT) {
            const int j0 = t * 64;
            const bool masked = (t == diagT);
            const int n0max = masked ? ((kmax - j0) >> 4) : 3;

            f32x4 st[4][2];
#pragma unroll
            for (int n0 = 0; n0 < 4; n0++) {
                if (masked && n0 > n0max) continue;
                bf16x8 kf[4];
#pragma unroll
                for (int kc = 0; kc < 4; kc++) {
                    int cpr = (kc * 4 + quad) ^ l15;
                    kf[kc] = *reinterpret_cast<const bf16x8*>(
                        Ks + (n0 * 16 + l15) * 128 + cpr * 8);
                }
#pragma unroll
                for (int m = 0; m < 2; m++) {
                    f32x4 acc = {};
#pragma unroll
                    for (int kc = 0; kc < 4; kc++)
                        acc = __builtin_amdgcn_mfma_f32_16x16x32_bf16(
                            kf[kc], qfrag[m][kc], acc, 0, 0, 0);
                    st[n0][m] = acc;
                }
            }

#pragma unroll
            for (int n0 = 0; n0 < 4; n0++) {
                if (masked && n0 > n0max) continue;
#pragma unroll
                for (int m = 0; m < 2; m++) {
                    uint32_t pk0, pk1;
                    float pv[4];
#pragma unroll
                    for (int r = 0; r < 4; r++) {
                        float p = exp2f(st[n0][m][r] * ATT_C1 - ATT_C2);
                        if (masked) {
                            int key = j0 + n0 * 16 + quad * 4 + r;
                            int q = qbase + m * 16 + l15;
                            if (key > q) p = 0.f;
                        }
                        uint32_t pb = f32_to_bf16(p);
                        pv[r] = bf16_to_f32(pb);
                        if (r == 0) pk0 = pb;
                        else if (r == 1) pk0 |= pb << 16;
                        else if (r == 2) pk1 = pb;
                        else pk1 |= pb << 16;
                    }
                    psum[m] += (pv[0] + pv[1]) + (pv[2] + pv[3]);
                    *reinterpret_cast<uint2*>(PsW + (m * 16 + l15) * 72 + n0 * 16 + quad * 4) =
                        make_uint2(pk0, pk1);
                }
            }

            const int kcend = masked ? (((kmax - j0) >> 5) + 1) : 2;
#pragma unroll
            for (int kc = 0; kc < 2; kc++) {
                if (kc >= kcend) continue;
                bf16x8 pf[2];
#pragma unroll
                for (int m = 0; m < 2; m++)
                    pf[m] = *reinterpret_cast<const bf16x8*>(
                        PsW + (m * 16 + l15) * 72 + kc * 32 + quad * 8);
#pragma unroll
                for (int n0 = 0; n0 < 8; n0++) {
                    int cpr = (kc * 4 + quad) ^ (l15 & 7);
                    bf16x8 vf = *reinterpret_cast<const bf16x8*>(
                        Vts + (n0 * 16 + l15) * 64 + cpr * 8);
#pragma unroll
                    for (int m = 0; m < 2; m++)
                        oacc[m][n0] = __builtin_amdgcn_mfma_f32_16x16x32_bf16(
                            pf[m], vf, oacc[m][n0], 0, 0, 0);
                }
            }
        }

        __syncthreads();  // all waves done reading Ks/Vts for tile t
        if (havenext) {
#pragma unroll
            for (int i = 0; i < 4; i++) {
                *reinterpret_cast<uint4*>(Ks + (wave * 4 + i) * 512 + lane * 8) = kpre[i];
                *reinterpret_cast<uint4*>(Vts + (wave * 4 + i) * 512 + lane * 8) = vpre[i];
            }
        }
        __syncthreads();  // tile t+1 visible
    }

#pragma unroll
    for (int m = 0; m < 2; m++) {
        float s = psum[m];
        s += __shfl_xor(s, 16);
        s += __shfl_xor(s, 32);
        psum[m] = 1.0f / s;
    }
    uint16_t* ybase = y + (size_t)(b * TLEN + qbase) * CDIM + h * DHEAD;
#pragma unroll
    for (int m = 0; m < 2; m++)
#pragma unroll
        for (int r = 0; r < 4; r++) {
            float inv = __shfl(psum[m], quad * 4 + r);
#pragma unroll
            for (int n0 = 0; n0 < 8; n0++)
                ybase[(size_t)(m * 16 + quad * 4 + r) * CDIM + n0 * 16 + l15] =
                    f32_to_bf16(oacc[m][n0][r] * inv);
        }
}

extern "C" void kernel_launch(void* const* d_in, const int* in_sizes, int n_in,
                              void* d_out, int out_size, void* d_ws, size_t ws_size,
                              hipStream_t stream) {
    const float* x = (const float*)d_in[0];       // [2,2048,2048]
    const float* w_attn = (const float*)d_in[1];  // [2048, 6144]
    const float* w_proj = (const float*)d_in[2];  // [2048, 2048]
    float* out = (float*)d_out;                   // [2,2048,2048]

    const int M = BDIM * TLEN;  // 4096
    const int K = CDIM;         // 2048
    const int N3 = 3 * CDIM;    // 6144

    char* ws = (char*)d_ws;
    uint16_t* xb = (uint16_t*)(ws);              // 16 MB: x bf16
    uint16_t* waT = (uint16_t*)(ws + 16777216);  // 24 MB: w_attn^T bf16 [6144][2048]
    uint16_t* wpT = (uint16_t*)(ws + 41943040);  // 8 MB: w_proj^T bf16 [2048][2048]
    uint16_t* qkp = (uint16_t*)(ws + 50331648);  // 32 MB: packed Q/K bf16 [4096][4096]
    uint16_t* vtb = (uint16_t*)(ws + 83886080);  // 16 MB: Vt bf16 [(b*16+h)*128+d][2048]
    uint16_t* yb = (uint16_t*)(ws + 100663296);  // 16 MB: y bf16 [4096][2048]

    // 1. cast x to bf16
    cvt_f32_bf16<<<(M * K / 4 + 255) / 256, 256, 0, stream>>>(x, xb, M * K);
    // 2. transpose+cast weights
    transpose_cvt<<<dim3(N3 / 64, K / 64), 256, 0, stream>>>(w_attn, waT, K, N3);
    transpose_cvt<<<dim3(K / 64, K / 64), 256, 0, stream>>>(w_proj, wpT, K, K);
    // 3. qkv = x @ w_attn; Q/K cols -> qkp (stride 4096), V cols -> vtb transposed
    //    grid 24x16 -> XCD rect 8m x 6n (xm=2)
    gemm_bf16_256<2><<<dim3(N3 / 256, M / 256), 512, 0, stream>>>(xb, waT, (void*)qkp, vtb, M, N3, K, 2);
    // 4. attention -> y bf16 [4096][2048]
    attn_mfma3<<<dim3(TLEN / 128, HDIM, BDIM), 256, 0, stream>>>(qkp, vtb, yb);
    // 5. out = y @ w_proj   fp32 [4096][2048]
    //    grid 8x16 -> XCD rect 4m x 4n (xm=4)
    gemm_bf16_256<0><<<dim3(K / 256, M / 256), 512, 0, stream>>>(yb, wpT, (void*)out, nullptr, M, K, K, 4);
}

// Round 10
// 414.116 us; speedup vs baseline: 1.2124x; 1.2124x over previous
//
#include <hip/hip_runtime.h>
#include <hip/hip_bf16.h>
#include <stdint.h>

#define TLEN 2048
#define CDIM 2048
#define BDIM 2
#define HDIM 16
#define DHEAD 128
// Q/K packed at stride 2*CDIM; V goes to a separate transposed buffer.
#define QROW ((size_t)(2 * CDIM))

typedef __bf16 bf16x8 __attribute__((ext_vector_type(8)));
typedef float f32x4 __attribute__((ext_vector_type(4)));

__device__ __forceinline__ uint16_t f32_to_bf16(float f) {
    uint32_t u = __builtin_bit_cast(uint32_t, f);
    uint32_t r = (u + 0x7FFFu + ((u >> 16) & 1u)) >> 16;
    return (uint16_t)r;
}
__device__ __forceinline__ float bf16_to_f32(uint32_t h) {
    uint32_t u = h << 16;
    return __builtin_bit_cast(float, u);
}

// async global->LDS, 16B per lane. LDS dest = wave-uniform base + lane*16;
// global source address is per-lane (gather) — used for swizzled staging.
__device__ __forceinline__ void gload_lds16(const uint16_t* g, uint16_t* l) {
    __builtin_amdgcn_global_load_lds(
        (const __attribute__((address_space(1))) uint32_t*)g,
        (__attribute__((address_space(3))) uint32_t*)l, 16, 0, 0);
}

// ---------------- elementwise f32 -> bf16 ----------------
__global__ void cvt_f32_bf16(const float* __restrict__ in, uint16_t* __restrict__ out, int n) {
    int i = (blockIdx.x * blockDim.x + threadIdx.x) * 4;
    if (i + 3 < n) {
        float4 f = *reinterpret_cast<const float4*>(in + i);
        ushort4 o;
        o.x = f32_to_bf16(f.x);
        o.y = f32_to_bf16(f.y);
        o.z = f32_to_bf16(f.z);
        o.w = f32_to_bf16(f.w);
        *reinterpret_cast<ushort4*>(out + i) = o;
    }
}

// ---------------- transpose + cast: in [R][Cc] f32 -> out [Cc][R] bf16 ----------------
__global__ __launch_bounds__(256) void transpose_cvt(const float* __restrict__ in,
                                                     uint16_t* __restrict__ out,
                                                     int R, int Cc) {
    __shared__ uint16_t tile[64][65];
    int c0 = blockIdx.x * 64;
    int r0 = blockIdx.y * 64;
    int tc = threadIdx.x & 63;
    int t4 = threadIdx.x >> 6;  // 0..3
    for (int rr = t4; rr < 64; rr += 4) {
        tile[rr][tc] = f32_to_bf16(in[(size_t)(r0 + rr) * Cc + c0 + tc]);
    }
    __syncthreads();
    int wr = threadIdx.x & 63;
    for (int cc = t4; cc < 64; cc += 4) {
        out[(size_t)(c0 + cc) * R + r0 + wr] = tile[wr][cc];
    }
}

// ====== 256x256 bf16 MFMA GEMM: half-unit LDS ring, 2-cluster/3-barrier tile ======
// (R6 body, verbatim — measured 128.6 µs QKV, no spill.)
// C[M][N] = A[M][K] * Bt[N][K]^T. 512 thr = 8 waves (2M x 4N); wave tile 128x64;
// BK=64; LDS ring of 4 half-unit slots per operand (even tiles slots 0/1, odd 2/3);
// tile t stages tile t+2's units. vmcnt ring: end-of-T vmcnt(8) retires T-1's 8
// stages (which loaded T+1). Edges: T+2>=nt -> no stage; T+1<nt -> vmcnt(0).
// Barriers only at true hazard points: B-slot WAR, A-slot WAR, t+1 visibility.
// Frag-live = aA(32)+bB(32) = 64 VGPR (R5's 96-VGPR read-ahead spilled: tripwire).
// XCD mapping: rectangular per-XCD tiling (R4; FETCH 176->90 MB verified).
// LDS swizzle: 16B-block c' = c ^ (row&7) via pre-swizzled global source.
// MODE 0: f32 out. MODE 2: QKV split — Q/K cols -> packed bf16 [M][2*CDIM],
// V cols -> transposed bf16 Vt[(b*16+h)*128+d][t].

#define RD8(P, OFF) (*reinterpret_cast<const bf16x8*>((P) + (OFF)))

#define RDA(DST, P, MB)                                         \
    _Pragma("unroll") for (int mi = 0; mi < 4; mi++) {          \
        DST[mi][0] = RD8(P, rdAo + ((MB) + mi) * 1024 + kblk0); \
        DST[mi][1] = RD8(P, rdAo + ((MB) + mi) * 1024 + kblk1); \
    }

#define RDB4(DST, P)                                   \
    _Pragma("unroll") for (int ni = 0; ni < 4; ni++) { \
        DST[ni][0] = RD8(P, rdBo + ni * 1024 + kblk0); \
        DST[ni][1] = RD8(P, rdBo + ni * 1024 + kblk1); \
    }

// 32 MFMA: k outer so each acc's two updates are 16 instructions apart.
#define MFMA32(MB)                                                    \
    _Pragma("unroll") for (int kk = 0; kk < 2; kk++)                  \
    _Pragma("unroll") for (int mi = 0; mi < 4; mi++)                  \
    _Pragma("unroll") for (int ni = 0; ni < 4; ni++)                  \
        acc[(MB) + mi][ni] = __builtin_amdgcn_mfma_f32_16x16x32_bf16( \
            aA[mi][kk], bB[ni][kk], acc[(MB) + mi][ni], 0, 0, 0);

#define TILE(S, T)                                           \
    {                                                        \
        const int k0 = (T) * 64;                             \
        const uint16_t* pA = As + ((S) + wrow) * 8192;       \
        const uint16_t* pB = Bs + ((S) + bsel) * 8192;       \
        RDB4(bB, pB)                                         \
        RDA(aA, pA, 0)                                       \
        asm volatile("s_waitcnt lgkmcnt(8)" ::: "memory");   \
        __builtin_amdgcn_s_barrier(); /* B reads done */     \
        if ((T) + 2 < nt) {                                  \
            stB((S), 0, k0 + 128);                           \
            stB((S), 1, k0 + 128);                           \
        }                                                    \
        asm volatile("s_waitcnt lgkmcnt(0)" ::: "memory");   \
        __builtin_amdgcn_sched_barrier(0);                   \
        __builtin_amdgcn_s_setprio(1);                       \
        MFMA32(0)                                            \
        __builtin_amdgcn_s_setprio(0);                       \
        RDA(aA, pA, 4)                                       \
        asm volatile("s_waitcnt lgkmcnt(0)" ::: "memory");   \
        __builtin_amdgcn_s_barrier(); /* A reads done */     \
        if ((T) + 2 < nt) {                                  \
            stA((S), 0, k0 + 128);                           \
            stA((S), 1, k0 + 128);                           \
        }                                                    \
        __builtin_amdgcn_sched_barrier(0);                   \
        __builtin_amdgcn_s_setprio(1);                       \
        MFMA32(4)                                            \
        __builtin_amdgcn_s_setprio(0);                       \
        if ((T) + 2 < nt) {                                  \
            asm volatile("s_waitcnt vmcnt(8)" ::: "memory"); \
        } else if ((T) + 1 < nt) {                           \
            asm volatile("s_waitcnt vmcnt(0)" ::: "memory"); \
        }                                                    \
        __builtin_amdgcn_s_barrier(); /* t+1 visible */      \
        __builtin_amdgcn_sched_barrier(0);                   \
    }

template <int MODE>
__global__ __launch_bounds__(512, 2) void gemm_bf16_256(const uint16_t* __restrict__ A,
                                                        const uint16_t* __restrict__ Bt,
                                                        void* __restrict__ Cp,
                                                        uint16_t* __restrict__ vt,
                                                        int M, int N, int K, int xm) {
    __shared__ __align__(16) uint16_t lds[65536];  // 128 KiB
    uint16_t* const As = lds;          // 4 ring slots x 8192 elems (128 rows x 64 K)
    uint16_t* const Bs = lds + 32768;  // 4 ring slots

    const int tid = threadIdx.x;
    const int wave = tid >> 6;
    const int lane = tid & 63;
    const int l15 = lane & 15;
    const int quad = lane >> 4;
    const int wrow = wave >> 2;  // 0..1 -> A half
    const int wcol = wave & 3;   // 0..3
    const int bsel = wcol >> 1;  // B half

    // rectangular XCD mapping (bijective; requires xm|gm and (8/xm)|gn).
    const int gm = gridDim.y, gn = gridDim.x;
    const int flat = blockIdx.y * gn + blockIdx.x;
    const int xcd = flat & 7;
    const int j = flat >> 3;  // 0 .. gm*gn/8 - 1
    const int xn = 8 / xm;
    const int RM = gm / xm;  // rect height (m-blocks)
    const int RN = gn / xn;  // rect width (n-blocks)
    const int m_blk = (xcd / xn) * RM + (j % RM);
    const int n_blk = (xcd % xn) * RN + (j / RM);
    const int m0 = m_blk * 256;
    const int n0 = n_blk * 256;

    // staging: lane -> row (lane>>3) within 8-row slab, source 16B-block
    // (lane&7) ^ (lane>>3) so that LDS (r, c') holds global block c' ^ (r&7).
    const int srow = wave * 8 + (lane >> 3);
    const int scol = ((lane & 7) ^ (lane >> 3)) * 8;
    const uint16_t* Ag = A + (size_t)(m0 + srow) * K + scol;
    const uint16_t* Bg = Bt + (size_t)(n0 + srow) * K + scol;
    const int ldsoff = wave * 512;

    // frag-read constants within a half-unit (row&7 == l15&7 for all frag rows)
    const int rdAo = l15 * 64;
    const int rdBo = ((wcol & 1) * 64 + l15) * 64;
    const int kblk0 = (quad ^ (l15 & 7)) * 8;
    const int kblk1 = ((4 + quad) ^ (l15 & 7)) * 8;

    const int nt = K >> 6;
    f32x4 acc[8][4] = {};
    bf16x8 aA[4][2], bB[4][2];

    auto stA = [&](int sb, int h, int kk) {
        const uint16_t* s = Ag + (size_t)(h * 128) * K + kk;
        uint16_t* d = As + (sb + h) * 8192 + ldsoff;
        gload_lds16(s, d);
        gload_lds16(s + (size_t)64 * K, d + 4096);
    };
    auto stB = [&](int sb, int h, int kk) {
        const uint16_t* s = Bg + (size_t)(h * 128) * K + kk;
        uint16_t* d = Bs + (sb + h) * 8192 + ldsoff;
        gload_lds16(s, d);
        gload_lds16(s + (size_t)64 * K, d + 4096);
    };

    // prologue: tile 0 -> slots 0/1, tile 1 -> slots 2/3 (16 loads);
    // vmcnt(8) retires tile-0 units; barrier gives cross-wave visibility.
    stB(0, 0, 0);
    stB(0, 1, 0);
    stA(0, 0, 0);
    stA(0, 1, 0);
    stB(2, 0, 64);
    stB(2, 1, 64);
    stA(2, 0, 64);
    stA(2, 1, 64);
    asm volatile("s_waitcnt vmcnt(8)" ::: "memory");
    __builtin_amdgcn_s_barrier();
    __builtin_amdgcn_sched_barrier(0);

    for (int t = 0; t < nt; t += 2) {
        TILE(0, t)
        TILE(2, t + 1)
    }

    const bool vmode = (MODE == 2) && (n0 >= 2 * CDIM);  // block-uniform
#pragma unroll
    for (int mi = 0; mi < 8; mi++)
#pragma unroll
        for (int ni = 0; ni < 4; ni++) {
            if (vmode) {
                // V cols: write transposed into Vt[(b*16+h)*128+d][t].
                int col = n0 + wcol * 64 + ni * 16 + l15;
                int vcol = col - 2 * CDIM;
                int hh = vcol >> 7, d = vcol & 127;
                int rowm = m0 + wrow * 128 + mi * 16 + quad * 4;
                int bb = rowm >> 11, tt = rowm & 2047;
                uint32_t lo = (uint32_t)f32_to_bf16(acc[mi][ni][0]) |
                              ((uint32_t)f32_to_bf16(acc[mi][ni][1]) << 16);
                uint32_t hi = (uint32_t)f32_to_bf16(acc[mi][ni][2]) |
                              ((uint32_t)f32_to_bf16(acc[mi][ni][3]) << 16);
                *reinterpret_cast<uint2*>(
                    vt + ((size_t)((bb * HDIM + hh) * DHEAD + d)) * TLEN + tt) =
                    make_uint2(lo, hi);
            } else {
#pragma unroll
                for (int r = 0; r < 4; r++) {
                    int row = m0 + wrow * 128 + mi * 16 + quad * 4 + r;
                    int col = n0 + wcol * 64 + ni * 16 + l15;
                    float v = acc[mi][ni][r];
                    if (MODE == 2)
                        ((uint16_t*)Cp)[(size_t)row * (2 * CDIM) + col] = f32_to_bf16(v);
                    else if (MODE == 1)
                        ((uint16_t*)Cp)[(size_t)row * N + col] = f32_to_bf16(v);
                    else
                        ((float*)Cp)[(size_t)row * N + col] = v;
                }
            }
        }
}

// ====== proj GEMM: 256x128 tile, 256 blocks (all CUs), half-unit ring ======
// R10: proj at 256x256 had grid 8x16 = 128 blocks -> HALF the CUs idle
// (budget closure from R9: proj ~125 us). This kernel: tile 256m x 128n,
// grid (N/128)x(M/256) = 16x16 = 256 blocks. 8 waves as 4m x 2n; wave tile
// 64x64; acc[4][4] (64 AGPR). A = 2 x 128-row units/tile (4-slot ring, even
// tiles slots 0/1, odd 2/3); B = 1 x 128-row unit/tile (2-slot ring, slot
// t&1). 6 stages/tile; stages for tile X issue during X-2; end-of-T vmcnt(6)
// retires T+1's 6. LDS 96 KiB. Same swizzle algebra as gemm_bf16_256.
__global__ __launch_bounds__(512, 2) void gemm_proj_256x128(
    const uint16_t* __restrict__ A, const uint16_t* __restrict__ Bt,
    float* __restrict__ C, int M, int N, int K) {
    __shared__ __align__(16) uint16_t lds[49152];  // 96 KiB
    uint16_t* const As = lds;          // 4 slots x 8192 (128 rows x 64 K)
    uint16_t* const Bs = lds + 32768;  // 2 slots x 8192

    const int tid = threadIdx.x;
    const int wave = tid >> 6;
    const int lane = tid & 63;
    const int l15 = lane & 15;
    const int quad = lane >> 4;
    const int wrow = wave >> 1;  // 0..3 -> 64-row slab of the 256 m-rows
    const int wcol = wave & 1;   // 0..1 -> 64-col slab of the 128 n-cols
    const int aunit = wrow >> 1; // which 128-row A unit

    // XCD rect mapping: gm=16, gn=16, xm=4, xn=2 -> RM=4, RN=8 (8 MB/XCD)
    const int gn = gridDim.x;
    const int flat = blockIdx.y * gn + blockIdx.x;
    const int xcd = flat & 7;
    const int j = flat >> 3;  // 0..31
    const int m_blk = (xcd >> 1) * 4 + (j & 3);
    const int n_blk = (xcd & 1) * 8 + (j >> 2);
    const int m0 = m_blk * 256;
    const int n0 = n_blk * 128;

    const int srow = wave * 8 + (lane >> 3);
    const int scol = ((lane & 7) ^ (lane >> 3)) * 8;
    const uint16_t* Ag = A + (size_t)(m0 + srow) * K + scol;
    const uint16_t* Bg = Bt + (size_t)(n0 + srow) * K + scol;
    const int ldsoff = wave * 512;

    // frag-read constants (row & 7 == l15 & 7 for all frag rows)
    const int rdAo = ((wrow & 1) * 64 + l15) * 64;
    const int rdBo = (wcol * 64 + l15) * 64;
    const int kblk0 = (quad ^ (l15 & 7)) * 8;
    const int kblk1 = ((4 + quad) ^ (l15 & 7)) * 8;

    const int nt = K >> 6;
    f32x4 acc[4][4] = {};
    bf16x8 aA[4][2], bB[4][2];

    auto stA = [&](int sb, int h, int kk) {
        const uint16_t* s = Ag + (size_t)(h * 128) * K + kk;
        uint16_t* d = As + (sb + h) * 8192 + ldsoff;
        gload_lds16(s, d);
        gload_lds16(s + (size_t)64 * K, d + 4096);
    };
    auto stB = [&](int sb, int kk) {
        const uint16_t* s = Bg + kk;
        uint16_t* d = Bs + sb * 8192 + ldsoff;
        gload_lds16(s, d);
        gload_lds16(s + (size_t)64 * K, d + 4096);
    };

    // prologue: tile0 -> B slot0 + A slots 0/1; tile1 -> B slot1 + A slots 2/3.
    // vmcnt(6) retires tile0's 6; tile1's 6 stay in flight.
    stB(0, 0);
    stA(0, 0, 0);
    stA(0, 1, 0);
    stB(1, 64);
    stA(2, 0, 64);
    stA(2, 1, 64);
    asm volatile("s_waitcnt vmcnt(6)" ::: "memory");
    __builtin_amdgcn_s_barrier();
    __builtin_amdgcn_sched_barrier(0);

#define PTILE(SA, SB, T)                                     \
    {                                                        \
        const int k0 = (T) * 64;                             \
        const uint16_t* pA = As + ((SA) + aunit) * 8192;     \
        const uint16_t* pB = Bs + (SB) * 8192;               \
        RDB4(bB, pB)                                         \
        RDA(aA, pA, 0)                                       \
        asm volatile("s_waitcnt lgkmcnt(8)" ::: "memory");   \
        __builtin_amdgcn_s_barrier(); /* B reads done */     \
        if ((T) + 2 < nt) stB((SB), k0 + 128);               \
        asm volatile("s_waitcnt lgkmcnt(0)" ::: "memory");   \
        __builtin_amdgcn_sched_barrier(0);                   \
        __builtin_amdgcn_s_setprio(1);                       \
        MFMA32(0)                                            \
        __builtin_amdgcn_s_setprio(0);                       \
        __builtin_amdgcn_s_barrier(); /* A reads done */     \
        if ((T) + 2 < nt) {                                  \
            stA((SA), 0, k0 + 128);                          \
            stA((SA), 1, k0 + 128);                          \
        }                                                    \
        __builtin_amdgcn_sched_barrier(0);                   \
        if ((T) + 2 < nt) {                                  \
            asm volatile("s_waitcnt vmcnt(6)" ::: "memory"); \
        } else if ((T) + 1 < nt) {                           \
            asm volatile("s_waitcnt vmcnt(0)" ::: "memory"); \
        }                                                    \
        __builtin_amdgcn_s_barrier(); /* t+1 visible */      \
        __builtin_amdgcn_sched_barrier(0);                   \
    }

    for (int t = 0; t < nt; t += 2) {
        PTILE(0, 0, t)
        PTILE(2, 1, t + 1)
    }
#undef PTILE

#pragma unroll
    for (int mi = 0; mi < 4; mi++)
#pragma unroll
        for (int ni = 0; ni < 4; ni++)
#pragma unroll
            for (int r = 0; r < 4; r++) {
                int row = m0 + wrow * 64 + mi * 16 + quad * 4 + r;
                int col = n0 + wcol * 64 + ni * 16 + l15;
                C[(size_t)row * N + col] = acc[mi][ni][r];
            }
}

// ---------------- MFMA flash attention v3 (R6 version, reverted) ----------------
// R9's T14 reg-prefetch regressed (198.6 us vs ~125; WRITE_SIZE 160 MB of
// scratch/write-amp traffic, occupancy 11.5%): 32 prefetch VGPRs live across
// the whole compute phase. Reverted to the measured-good global_load_lds form.
#define ATT_C1 0.12751743f
#define ATT_C2 17.3123405f

__global__ __launch_bounds__(256) void attn_mfma3(const uint16_t* __restrict__ qkv,
                                                  const uint16_t* __restrict__ vtg,
                                                  uint16_t* __restrict__ y) {
    __shared__ __align__(16) uint16_t Ks[64 * 128];    // swizzled: c' = c ^ (key&15)
    __shared__ __align__(16) uint16_t Vts[128 * 64];   // swizzled: c' = c ^ (d&7)
    __shared__ __align__(16) uint16_t Ps[4][32 * 72];  // per-wave P [q][key]

    const int tid = threadIdx.x;
    const int wave = tid >> 6;
    const int lane = tid & 63;
    const int l15 = lane & 15;
    const int quad = lane >> 4;
    const int h = blockIdx.y;
    const int b = blockIdx.z;
    const int qblk = (int)gridDim.x - 1 - (int)blockIdx.x;
    const int qbase = qblk * 128 + wave * 32;
    const int kmax = qbase + 31;

    const uint16_t* kg = qkv + (size_t)b * TLEN * QROW + CDIM + h * DHEAD;
    const uint16_t* vg = vtg + (size_t)(b * HDIM + h) * DHEAD * TLEN;
    uint16_t* PsW = Ps[wave];

    int koff[4], voff[4];
#pragma unroll
    for (int i = 0; i < 4; i++) {
        int Lb = (wave * 4 + i) * 64 + lane;
        int key = Lb >> 4;
        int ck = (Lb & 15) ^ (key & 15);
        koff[i] = key * (int)QROW + ck * 8;
        int d = Lb >> 3;
        int cv = (Lb & 7) ^ (d & 7);
        voff[i] = d * TLEN + cv * 8;
    }

    bf16x8 qfrag[2][4];
#pragma unroll
    for (int m = 0; m < 2; m++) {
        const uint16_t* qp =
            qkv + (size_t)(b * TLEN + qbase + m * 16 + l15) * QROW + h * DHEAD + quad * 8;
#pragma unroll
        for (int kc = 0; kc < 4; kc++)
            qfrag[m][kc] = *reinterpret_cast<const bf16x8*>(qp + kc * 32);
    }

    f32x4 oacc[2][8] = {};
    float psum[2] = {0.f, 0.f};

    const int diagT = qblk * 2 + (wave >> 1);
    const int ntiles = qblk * 2 + 2;

    for (int t = 0; t < ntiles; t++) {
        const int j0 = t * 64;
        if (t > 0) __syncthreads();
        {
            const uint16_t* kj = kg + (size_t)j0 * QROW;
            const uint16_t* vj = vg + j0;
#pragma unroll
            for (int i = 0; i < 4; i++) {
                gload_lds16(kj + koff[i], Ks + (wave * 4 + i) * 512);
                gload_lds16(vj + voff[i], Vts + (wave * 4 + i) * 512);
            }
        }
        __syncthreads();
        if (t > diagT) continue;

        const bool masked = (t == diagT);
        const int n0max = masked ? ((kmax - j0) >> 4) : 3;

        f32x4 st[4][2];
#pragma unroll
        for (int n0 = 0; n0 < 4; n0++) {
            if (masked && n0 > n0max) continue;
            bf16x8 kf[4];
#pragma unroll
            for (int kc = 0; kc < 4; kc++) {
                int cpr = (kc * 4 + quad) ^ l15;
                kf[kc] = *reinterpret_cast<const bf16x8*>(
                    Ks + (n0 * 16 + l15) * 128 + cpr * 8);
            }
#pragma unroll
            for (int m = 0; m < 2; m++) {
                f32x4 acc = {};
#pragma unroll
                for (int kc = 0; kc < 4; kc++)
                    acc = __builtin_amdgcn_mfma_f32_16x16x32_bf16(
                        kf[kc], qfrag[m][kc], acc, 0, 0, 0);
                st[n0][m] = acc;
            }
        }

#pragma unroll
        for (int n0 = 0; n0 < 4; n0++) {
            if (masked && n0 > n0max) continue;
#pragma unroll
            for (int m = 0; m < 2; m++) {
                uint32_t pk0, pk1;
                float pv[4];
#pragma unroll
                for (int r = 0; r < 4; r++) {
                    float p = exp2f(st[n0][m][r] * ATT_C1 - ATT_C2);
                    if (masked) {
                        int key = j0 + n0 * 16 + quad * 4 + r;
                        int q = qbase + m * 16 + l15;
                        if (key > q) p = 0.f;
                    }
                    uint32_t pb = f32_to_bf16(p);
                    pv[r] = bf16_to_f32(pb);
                    if (r == 0) pk0 = pb;
                    else if (r == 1) pk0 |= pb << 16;
                    else if (r == 2) pk1 = pb;
                    else pk1 |= pb << 16;
                }
                psum[m] += (pv[0] + pv[1]) + (pv[2] + pv[3]);
                *reinterpret_cast<uint2*>(PsW + (m * 16 + l15) * 72 + n0 * 16 + quad * 4) =
                    make_uint2(pk0, pk1);
            }
        }

        const int kcend = masked ? (((kmax - j0) >> 5) + 1) : 2;
#pragma unroll
        for (int kc = 0; kc < 2; kc++) {
            if (kc >= kcend) continue;
            bf16x8 pf[2];
#pragma unroll
            for (int m = 0; m < 2; m++)
                pf[m] = *reinterpret_cast<const bf16x8*>(
                    PsW + (m * 16 + l15) * 72 + kc * 32 + quad * 8);
#pragma unroll
            for (int n0 = 0; n0 < 8; n0++) {
                int cpr = (kc * 4 + quad) ^ (l15 & 7);
                bf16x8 vf = *reinterpret_cast<const bf16x8*>(
                    Vts + (n0 * 16 + l15) * 64 + cpr * 8);
#pragma unroll
                for (int m = 0; m < 2; m++)
                    oacc[m][n0] = __builtin_amdgcn_mfma_f32_16x16x32_bf16(
                        pf[m], vf, oacc[m][n0], 0, 0, 0);
            }
        }
    }

#pragma unroll
    for (int m = 0; m < 2; m++) {
        float s = psum[m];
        s += __shfl_xor(s, 16);
        s += __shfl_xor(s, 32);
        psum[m] = 1.0f / s;
    }
    uint16_t* ybase = y + (size_t)(b * TLEN + qbase) * CDIM + h * DHEAD;
#pragma unroll
    for (int m = 0; m < 2; m++)
#pragma unroll
        for (int r = 0; r < 4; r++) {
            float inv = __shfl(psum[m], quad * 4 + r);
#pragma unroll
            for (int n0 = 0; n0 < 8; n0++)
                ybase[(size_t)(m * 16 + quad * 4 + r) * CDIM + n0 * 16 + l15] =
                    f32_to_bf16(oacc[m][n0][r] * inv);
        }
}

extern "C" void kernel_launch(void* const* d_in, const int* in_sizes, int n_in,
                              void* d_out, int out_size, void* d_ws, size_t ws_size,
                              hipStream_t stream) {
    const float* x = (const float*)d_in[0];       // [2,2048,2048]
    const float* w_attn = (const float*)d_in[1];  // [2048, 6144]
    const float* w_proj = (const float*)d_in[2];  // [2048, 2048]
    float* out = (float*)d_out;                   // [2,2048,2048]

    const int M = BDIM * TLEN;  // 4096
    const int K = CDIM;         // 2048
    const int N3 = 3 * CDIM;    // 6144

    char* ws = (char*)d_ws;
    uint16_t* xb = (uint16_t*)(ws);              // 16 MB: x bf16
    uint16_t* waT = (uint16_t*)(ws + 16777216);  // 24 MB: w_attn^T bf16 [6144][2048]
    uint16_t* wpT = (uint16_t*)(ws + 41943040);  // 8 MB: w_proj^T bf16 [2048][2048]
    uint16_t* qkp = (uint16_t*)(ws + 50331648);  // 32 MB: packed Q/K bf16 [4096][4096]
    uint16_t* vtb = (uint16_t*)(ws + 83886080);  // 16 MB: Vt bf16 [(b*16+h)*128+d][2048]
    uint16_t* yb = (uint16_t*)(ws + 100663296);  // 16 MB: y bf16 [4096][2048]

    // 1. cast x to bf16
    cvt_f32_bf16<<<(M * K / 4 + 255) / 256, 256, 0, stream>>>(x, xb, M * K);
    // 2. transpose+cast weights
    transpose_cvt<<<dim3(N3 / 64, K / 64), 256, 0, stream>>>(w_attn, waT, K, N3);
    transpose_cvt<<<dim3(K / 64, K / 64), 256, 0, stream>>>(w_proj, wpT, K, K);
    // 3. qkv = x @ w_attn; Q/K cols -> qkp (stride 4096), V cols -> vtb transposed
    //    grid 24x16 -> XCD rect 8m x 6n (xm=2)
    gemm_bf16_256<2><<<dim3(N3 / 256, M / 256), 512, 0, stream>>>(xb, waT, (void*)qkp, vtb, M, N3, K, 2);
    // 4. attention -> y bf16 [4096][2048]
    attn_mfma3<<<dim3(TLEN / 128, HDIM, BDIM), 256, 0, stream>>>(qkp, vtb, yb);
    // 5. out = y @ w_proj   fp32 [4096][2048] — 256x128 tiles, 256 blocks (all CUs)
    gemm_proj_256x128<<<dim3(K / 128, M / 256), 512, 0, stream>>>(yb, wpT, out, M, K, K);
}